// Round 3
// baseline (613.408 us; speedup 1.0000x reference)
//
#include <hip/hip_runtime.h>
#include <hip/hip_bf16.h>

// out[b,o] = sum_g as[b,g]*ws[o,g]*dot(x4[b,g*128..],w4[o,..]) + bias[o]
// B=4096, O=11008, K=4096, GS=128, G=32. Inputs normalized by harness to f32.
// R3: prepass int4->int8 (16B/thread stores) + scale transpose; GEMM = i8 MFMA
//     with DOUBLE-BUFFERED LDS prefetch (1 barrier/group, drain-free) and
//     hoisted scale loads. 128x128 tile, 256 thr, per-group i32->f32 rescale.

#define B_DIM 4096
#define O_DIM 11008
#define K_DIM 4096
#define G_NUM 32

#define NX32 8388608u    // int32 elements of xq (4096*2048)
#define NW32 22544384u   // int32 elements of wq (11008*2048)
#define X8_BYTES  16777216u
#define W8_BYTES  45088768u

typedef int   i32x4 __attribute__((ext_vector_type(4)));
typedef float f32x4 __attribute__((ext_vector_type(4)));

// ---------------- prepass 1: unpack nibbles -> signed int8, 8 int32 -> 16B ----------------
__device__ __forceinline__ unsigned pack2(int v) {
    int t = v ^ 0x88;                                  // (q^8)-8 per nibble
    unsigned lo = (unsigned)(((t & 15) - 8) & 0xFF);
    unsigned hi = (unsigned)((((t >> 4) & 15) - 8) & 0xFF);
    return lo | (hi << 8);
}

__global__ __launch_bounds__(256)
void unpack_kernel(const int* __restrict__ xq, const int* __restrict__ wq,
                   unsigned char* __restrict__ X8, unsigned char* __restrict__ W8) {
    unsigned t = blockIdx.x * 256u + threadIdx.x;      // one thread = 8 int32 -> 16 bytes
    const int* src;
    unsigned char* dst;
    if (t < NX32 / 8) {                                // blocks 0..4095 are X exactly
        src = xq + (size_t)t * 8;
        dst = X8 + (size_t)t * 16;
    } else {
        unsigned j = t - NX32 / 8;
        src = wq + (size_t)j * 8;
        dst = W8 + (size_t)j * 16;
    }
    int4 v0 = ((const int4*)src)[0];
    int4 v1 = ((const int4*)src)[1];
    uint4 o;
    o.x = pack2(v0.x) | (pack2(v0.y) << 16);
    o.y = pack2(v0.z) | (pack2(v0.w) << 16);
    o.z = pack2(v1.x) | (pack2(v1.y) << 16);
    o.w = pack2(v1.z) | (pack2(v1.w) << 16);
    *(uint4*)dst = o;
}

// ---------------- prepass 2: transpose scales to [g][row] ----------------
__global__ __launch_bounds__(256)
void tscale_kernel(const float* __restrict__ as_, const float* __restrict__ ws_,
                   float* __restrict__ asT, float* __restrict__ wsT) {
    int bx = blockIdx.x, g = blockIdx.y, t = threadIdx.x;
    if (bx < 16) {
        int b = bx * 256 + t;
        asT[g * B_DIM + b] = as_[(size_t)b * G_NUM + g];
    } else {
        int o = (bx - 16) * 256 + t;
        wsT[(size_t)g * O_DIM + o] = ws_[(size_t)o * G_NUM + g];
    }
}

// ---------------- GEMM: i8 MFMA, double-buffered LDS, per-group rescale ----------------
__global__ __launch_bounds__(256, 2)
void gemm_i8(const unsigned char* __restrict__ X8, const unsigned char* __restrict__ W8,
             const float* __restrict__ asT, const float* __restrict__ wsT,
             const float* __restrict__ bias, float* __restrict__ out) {
    __shared__ __align__(16) unsigned char A8[2][16384];
    __shared__ __align__(16) unsigned char B8[2][16384];

    const int tid  = threadIdx.x;
    const int wv   = tid >> 6;
    const int lane = tid & 63;
    const int quad = lane >> 4;
    const int lq   = lane & 15;
    const int bm   = blockIdx.x;
    const int bn   = blockIdx.y;
    const int wm   = (wv & 1) << 6;
    const int wn   = (wv >> 1) << 6;

    f32x4 facc[4][4] = {};

    // staging geometry: wave wv stages slabs wv*4..wv*4+3 (8 rows x 128B each) for A and B.
    // physical LDS chunk p of row r holds logical chunk p^(r&7) (XOR swizzle, conflict-free reads).
    const int l8 = lane >> 3;
    const int c8 = lane & 7;
    const int sw_chunk = ((c8 ^ l8) << 4);
    const size_t xrow0 = (size_t)(bm * 128) * K_DIM;
    const size_t wrow0 = (size_t)(bn * 128) * K_DIM;

    auto stage = [&](int g, int buf) {
        const int gb = g << 7;
#pragma unroll
        for (int s = 0; s < 4; ++s) {
            const int slab = (wv << 2) + s;
            const int row  = (slab << 3) + l8;
            const unsigned char* gpA = X8 + xrow0 + (size_t)row * K_DIM + gb + sw_chunk;
            const unsigned char* gpB = W8 + wrow0 + (size_t)row * K_DIM + gb + sw_chunk;
            __builtin_amdgcn_global_load_lds(
                (const __attribute__((address_space(1))) void*)gpA,
                (__attribute__((address_space(3))) void*)(&A8[buf][0] + (slab << 10)), 16, 0, 0);
            __builtin_amdgcn_global_load_lds(
                (const __attribute__((address_space(1))) void*)gpB,
                (__attribute__((address_space(3))) void*)(&B8[buf][0] + (slab << 10)), 16, 0, 0);
        }
    };

    stage(0, 0);

    for (int g = 0; g < G_NUM; ++g) {
        const int buf = g & 1;

        // scale loads for THIS group, issued before the prefetch so their waitcnt
        // does not drain the prefetch (vmcnt counts newest-first).
        f32x4 asr[4];
        float wsn[4];
#pragma unroll
        for (int i = 0; i < 4; ++i)
            asr[i] = *(const f32x4*)&asT[(g << 12) + bm * 128 + wm + (i << 4) + (quad << 2)];
#pragma unroll
        for (int j = 0; j < 4; ++j)
            wsn[j] = wsT[(size_t)g * O_DIM + bn * 128 + wn + (j << 4) + lq];

        __syncthreads();              // drains stage(g) — issued one full compute phase ago

        if (g + 1 < G_NUM) stage(g + 1, buf ^ 1);   // prefetch flies during compute(g)

        i32x4 gacc[4][4] = {};
#pragma unroll
        for (int ks = 0; ks < 2; ++ks) {
            i32x4 av[4], bv[4];
            const int pa = ((((ks << 2) + quad) ^ (lq & 7)) << 4);
#pragma unroll
            for (int i = 0; i < 4; ++i) {
                av[i] = *(const i32x4*)&A8[buf][((wm + (i << 4) + lq) << 7) + pa];
                bv[i] = *(const i32x4*)&B8[buf][((wn + (i << 4) + lq) << 7) + pa];
            }
#pragma unroll
            for (int i = 0; i < 4; ++i)
#pragma unroll
                for (int j = 0; j < 4; ++j)
                    gacc[i][j] = __builtin_amdgcn_mfma_i32_16x16x64_i8(av[i], bv[j], gacc[i][j], 0, 0, 0);
        }

        // rescale: C/D layout col=lq, row=quad*4+r
#pragma unroll
        for (int i = 0; i < 4; ++i)
#pragma unroll
            for (int j = 0; j < 4; ++j)
#pragma unroll
                for (int r = 0; r < 4; ++r)
                    facc[i][j][r] = __builtin_fmaf(asr[i][r] * wsn[j], (float)gacc[i][j][r], facc[i][j][r]);
    }

    // epilogue (f32 output)
    const int n0 = bn * 128 + wn + lq;
    const int m0 = bm * 128 + wm + (quad << 2);
    float bvs[4];
#pragma unroll
    for (int j = 0; j < 4; ++j) bvs[j] = bias[n0 + (j << 4)];
#pragma unroll
    for (int i = 0; i < 4; ++i) {
#pragma unroll
        for (int r = 0; r < 4; ++r) {
            float* orow = out + (size_t)(m0 + (i << 4) + r) * O_DIM;
#pragma unroll
            for (int j = 0; j < 4; ++j)
                orow[n0 + (j << 4)] = facc[i][j][r] + bvs[j];
        }
    }
}

extern "C" void kernel_launch(void* const* d_in, const int* in_sizes, int n_in,
                              void* d_out, int out_size, void* d_ws, size_t ws_size,
                              hipStream_t stream) {
    const int*   xq   = (const int*)d_in[0];
    const float* as_  = (const float*)d_in[1];
    const int*   wq   = (const int*)d_in[2];
    const float* ws_  = (const float*)d_in[3];
    const float* bias = (const float*)d_in[4];
    float* out        = (float*)d_out;

    unsigned char* X8 = (unsigned char*)d_ws;
    unsigned char* W8 = X8 + X8_BYTES;
    float* asT = (float*)((unsigned char*)d_ws + X8_BYTES + W8_BYTES);
    float* wsT = asT + (size_t)G_NUM * B_DIM;

    unpack_kernel<<<(NX32 + NW32) / 8 / 256, 256, 0, stream>>>(xq, wq, X8, W8);
    tscale_kernel<<<dim3(59, 32), 256, 0, stream>>>(as_, ws_, asT, wsT);
    gemm_i8<<<dim3(B_DIM / 128, O_DIM / 128), 256, 0, stream>>>(X8, W8, asT, wsT, bias, out);
}

// Round 4
// 524.225 us; speedup vs baseline: 1.1701x; 1.1701x over previous
//
#include <hip/hip_runtime.h>
#include <hip/hip_bf16.h>

// out[b,o] = sum_g as[b,g]*ws[o,g]*dot(x4[b,g*128..],w4[o,..]) + bias[o]
// B=4096, O=11008, K=4096, GS=128, G=32. Inputs normalized by harness to f32.
// R4: prepass int4->int8 + scale transpose; GEMM = i8 MFMA with double-buffered
//     LDS using FOUR STATIC __shared__ arrays (alias-analysis-friendly) and a
//     2x-unrolled group loop -> prefetch truly overlaps compute. 128x128 tile.

#define B_DIM 4096
#define O_DIM 11008
#define K_DIM 4096
#define G_NUM 32

#define NX32 8388608u    // int32 elements of xq
#define NW32 22544384u   // int32 elements of wq
#define X8_BYTES  16777216u
#define W8_BYTES  45088768u

typedef int   i32x4 __attribute__((ext_vector_type(4)));
typedef float f32x4 __attribute__((ext_vector_type(4)));

// ---------------- prepass 1: unpack nibbles -> signed int8 ----------------
__device__ __forceinline__ unsigned pack2(int v) {
    int t = v ^ 0x88;                                  // (q^8)-8 per nibble
    unsigned lo = (unsigned)(((t & 15) - 8) & 0xFF);
    unsigned hi = (unsigned)((((t >> 4) & 15) - 8) & 0xFF);
    return lo | (hi << 8);
}

__global__ __launch_bounds__(256)
void unpack_kernel(const int* __restrict__ xq, const int* __restrict__ wq,
                   unsigned char* __restrict__ X8, unsigned char* __restrict__ W8) {
    unsigned t = blockIdx.x * 256u + threadIdx.x;      // one thread: 8 int32 -> 16 B
    const int* src;
    unsigned char* dst;
    if (t < NX32 / 8) {
        src = xq + (size_t)t * 8;
        dst = X8 + (size_t)t * 16;
    } else {
        unsigned j = t - NX32 / 8;
        src = wq + (size_t)j * 8;
        dst = W8 + (size_t)j * 16;
    }
    int4 v0 = ((const int4*)src)[0];
    int4 v1 = ((const int4*)src)[1];
    uint4 o;
    o.x = pack2(v0.x) | (pack2(v0.y) << 16);
    o.y = pack2(v0.z) | (pack2(v0.w) << 16);
    o.z = pack2(v1.x) | (pack2(v1.y) << 16);
    o.w = pack2(v1.z) | (pack2(v1.w) << 16);
    *(uint4*)dst = o;
}

// ---------------- prepass 2: transpose scales to [g][row] ----------------
__global__ __launch_bounds__(256)
void tscale_kernel(const float* __restrict__ as_, const float* __restrict__ ws_,
                   float* __restrict__ asT, float* __restrict__ wsT) {
    int bx = blockIdx.x, g = blockIdx.y, t = threadIdx.x;
    if (bx < 16) {
        int b = bx * 256 + t;
        asT[g * B_DIM + b] = as_[(size_t)b * G_NUM + g];
    } else {
        int o = (bx - 16) * 256 + t;
        wsT[(size_t)g * O_DIM + o] = ws_[(size_t)o * G_NUM + g];
    }
}

// ---------------- GEMM ----------------
__global__ __launch_bounds__(256, 2)
void gemm_i8(const unsigned char* __restrict__ X8, const unsigned char* __restrict__ W8,
             const float* __restrict__ asT, const float* __restrict__ wsT,
             const float* __restrict__ bias, float* __restrict__ out) {
    // four statically distinct LDS objects -> compiler can prove prefetch(buf1)
    // does not alias ds_reads(buf0) and vice versa.
    __shared__ __align__(16) unsigned char A0[16384];
    __shared__ __align__(16) unsigned char B0[16384];
    __shared__ __align__(16) unsigned char A1[16384];
    __shared__ __align__(16) unsigned char B1[16384];

    const int tid  = threadIdx.x;
    const int wv   = tid >> 6;
    const int lane = tid & 63;
    const int quad = lane >> 4;
    const int lq   = lane & 15;
    const int bm   = blockIdx.x;
    const int bn   = blockIdx.y;
    const int wm   = (wv & 1) << 6;
    const int wn   = (wv >> 1) << 6;

    f32x4 facc[4][4] = {};

    const int l8 = lane >> 3;
    const int c8 = lane & 7;
    const int sw_chunk = ((c8 ^ l8) << 4);            // XOR store-side swizzle
    const size_t xrow0 = (size_t)(bm * 128) * K_DIM;
    const size_t wrow0 = (size_t)(bn * 128) * K_DIM;

    auto stage = [&](int g, unsigned char* Ad, unsigned char* Bd) {
        const int gb = g << 7;
#pragma unroll
        for (int s = 0; s < 4; ++s) {
            const int slab = (wv << 2) + s;
            const int row  = (slab << 3) + l8;
            const unsigned char* gpA = X8 + xrow0 + (size_t)row * K_DIM + gb + sw_chunk;
            const unsigned char* gpB = W8 + wrow0 + (size_t)row * K_DIM + gb + sw_chunk;
            __builtin_amdgcn_global_load_lds(
                (const __attribute__((address_space(1))) void*)gpA,
                (__attribute__((address_space(3))) void*)(Ad + (slab << 10)), 16, 0, 0);
            __builtin_amdgcn_global_load_lds(
                (const __attribute__((address_space(1))) void*)gpB,
                (__attribute__((address_space(3))) void*)(Bd + (slab << 10)), 16, 0, 0);
        }
    };

    auto compute = [&](int g, const unsigned char* Ab, const unsigned char* Bb) {
        // scale loads: issued now, consumed after the MFMA chain -> latency hidden
        f32x4 asr[4];
        float wsn[4];
#pragma unroll
        for (int i = 0; i < 4; ++i)
            asr[i] = *(const f32x4*)&asT[(g << 12) + bm * 128 + wm + (i << 4) + (quad << 2)];
#pragma unroll
        for (int j = 0; j < 4; ++j)
            wsn[j] = wsT[(size_t)g * O_DIM + bn * 128 + wn + (j << 4) + lq];

        i32x4 gacc[4][4] = {};
#pragma unroll
        for (int ks = 0; ks < 2; ++ks) {
            i32x4 av[4], bv[4];
            const int pa = ((((ks << 2) + quad) ^ (lq & 7)) << 4);
#pragma unroll
            for (int i = 0; i < 4; ++i) {
                av[i] = *(const i32x4*)&Ab[((wm + (i << 4) + lq) << 7) + pa];
                bv[i] = *(const i32x4*)&Bb[((wn + (i << 4) + lq) << 7) + pa];
            }
#pragma unroll
            for (int i = 0; i < 4; ++i)
#pragma unroll
                for (int j = 0; j < 4; ++j)
                    gacc[i][j] = __builtin_amdgcn_mfma_i32_16x16x64_i8(av[i], bv[j], gacc[i][j], 0, 0, 0);
        }
#pragma unroll
        for (int i = 0; i < 4; ++i)
#pragma unroll
            for (int j = 0; j < 4; ++j)
#pragma unroll
                for (int r = 0; r < 4; ++r)
                    facc[i][j][r] = __builtin_fmaf(asr[i][r] * wsn[j], (float)gacc[i][j][r], facc[i][j][r]);
    };

    stage(0, A0, B0);

    for (int g2 = 0; g2 < G_NUM; g2 += 2) {
        __syncthreads();                     // drains stage(g2) — issued a full phase ago
        stage(g2 + 1, A1, B1);               // flies during compute(g2)
        compute(g2, A0, B0);

        __syncthreads();                     // drains stage(g2+1) — issued a phase ago
        if (g2 + 2 < G_NUM) stage(g2 + 2, A0, B0);
        compute(g2 + 1, A1, B1);
    }

    // epilogue (f32 output); C/D: col=lq, row=quad*4+r
    const int n0 = bn * 128 + wn + lq;
    const int m0 = bm * 128 + wm + (quad << 2);
    float bvs[4];
#pragma unroll
    for (int j = 0; j < 4; ++j) bvs[j] = bias[n0 + (j << 4)];
#pragma unroll
    for (int i = 0; i < 4; ++i) {
#pragma unroll
        for (int r = 0; r < 4; ++r) {
            float* orow = out + (size_t)(m0 + (i << 4) + r) * O_DIM;
#pragma unroll
            for (int j = 0; j < 4; ++j)
                orow[n0 + (j << 4)] = facc[i][j][r] + bvs[j];
        }
    }
}

extern "C" void kernel_launch(void* const* d_in, const int* in_sizes, int n_in,
                              void* d_out, int out_size, void* d_ws, size_t ws_size,
                              hipStream_t stream) {
    const int*   xq   = (const int*)d_in[0];
    const float* as_  = (const float*)d_in[1];
    const int*   wq   = (const int*)d_in[2];
    const float* ws_  = (const float*)d_in[3];
    const float* bias = (const float*)d_in[4];
    float* out        = (float*)d_out;

    unsigned char* X8 = (unsigned char*)d_ws;
    unsigned char* W8 = X8 + X8_BYTES;
    float* asT = (float*)((unsigned char*)d_ws + X8_BYTES + W8_BYTES);
    float* wsT = asT + (size_t)G_NUM * B_DIM;

    unpack_kernel<<<(NX32 + NW32) / 8 / 256, 256, 0, stream>>>(xq, wq, X8, W8);
    tscale_kernel<<<dim3(59, 32), 256, 0, stream>>>(as_, ws_, asT, wsT);
    gemm_i8<<<dim3(B_DIM / 128, O_DIM / 128), 256, 0, stream>>>(X8, W8, asT, wsT, bias, out);
}